// Round 1
// baseline (2126.151 us; speedup 1.0000x reference)
//
#include <hip/hip_runtime.h>
#include <cstdint>
#include <cstddef>

// ---------------------------------------------------------------------------
// JetFFNMoEBlock: x + attn(rmsnorm(x)) -> x2; x2 + moe(rmsnorm(x2)); aux loss.
// Precision strategy: fp32 for everything feeding the router (expert selection
// must match the fp32 reference: logit gaps can be ~1e-4, bf16 noise would flip
// top-2 picks and blow absmax). bf16 MFMA for the expert GEMMs (post-selection,
// purely additive error ~5e-3 << 0.1175 threshold).
// ---------------------------------------------------------------------------

typedef unsigned short u16;
typedef __attribute__((ext_vector_type(8))) short bf16x8;   // 8 bf16 in 4 VGPRs
typedef __attribute__((ext_vector_type(4))) float f32x4;

#define HDIM 1024
#define NTOK 4096
#define SEQ  1024
#define NHEADS 16
#define FF 4096
#define NEXP 8
#define MAXTILE 72   // sum_e ceil(cnt_e/128) <= 8192/128 + 7 = 71

__device__ __forceinline__ u16 f2bf(float f) {
  uint32_t u = __float_as_uint(f);
  u = (u + 0x7FFFu + ((u >> 16) & 1u)) >> 16;   // RNE
  return (u16)u;
}

__device__ __forceinline__ float gelu_f(float x) {
  // tanh-approx gelu (jax.nn.gelu default). tanh via 1 - 2/(e^{2u}+1): inf-safe.
  float u = 0.7978845608028654f * (x + 0.044715f * x * x * x);
  float ex = __expf(2.0f * u);
  return 0.5f * x * (1.0f + (1.0f - 2.0f / (ex + 1.0f)));
}

__device__ __forceinline__ float dot4(float4 a, float4 b) {
  return a.x * b.x + a.y * b.y + a.z * b.z + a.w * b.w;
}

// ---------------------------------------------------------------------------
// RMSNorm: one block per row of 1024. Optionally emits bf16 copy.
// ---------------------------------------------------------------------------
__global__ __launch_bounds__(256) void rmsnorm_kernel(
    const float* __restrict__ x, const float* __restrict__ g,
    float* __restrict__ outf, u16* __restrict__ outb, int wbf) {
  int row = blockIdx.x;
  int t = threadIdx.x;
  const float4 xv = ((const float4*)(x + (size_t)row * HDIM))[t];
  float ss = xv.x * xv.x + xv.y * xv.y + xv.z * xv.z + xv.w * xv.w;
#pragma unroll
  for (int off = 32; off; off >>= 1) ss += __shfl_xor(ss, off);
  __shared__ float wsum[4];
  if ((t & 63) == 0) wsum[t >> 6] = ss;
  __syncthreads();
  float tot = wsum[0] + wsum[1] + wsum[2] + wsum[3];
  float scale = 1.0f / sqrtf(tot * (1.0f / HDIM) + 1e-5f);
  const float4 gv = ((const float4*)g)[t];
  float4 o;
  o.x = xv.x * scale * gv.x; o.y = xv.y * scale * gv.y;
  o.z = xv.z * scale * gv.z; o.w = xv.w * scale * gv.w;
  ((float4*)(outf + (size_t)row * HDIM))[t] = o;
  if (wbf) {
    uint2 p;
    p.x = (uint32_t)f2bf(o.x) | ((uint32_t)f2bf(o.y) << 16);
    p.y = (uint32_t)f2bf(o.z) | ((uint32_t)f2bf(o.w) << 16);
    ((uint2*)(outb + (size_t)row * HDIM))[t] = p;
  }
}

// ---------------------------------------------------------------------------
// fp32 SGEMM  C[M,N] = A[M,K] @ B[K,N]  (row-major). 128x128 tile, BK=16,
// 256 threads, 8x8 per thread. mode 1: C = A@B + resid (writes d_out = x2).
// ---------------------------------------------------------------------------
__global__ __launch_bounds__(256) void sgemm_kernel(
    const float* __restrict__ A, const float* __restrict__ B,
    float* __restrict__ C, const float* __restrict__ resid,
    int M, int N, int K, int mode) {
  __shared__ float As[16][132];  // [k][m], pad to break conflicts
  __shared__ float Bs[16][132];  // [k][n]
  int t = threadIdx.x;
  int tx = t & 15, ty = t >> 4;
  int m0 = blockIdx.y * 128, n0 = blockIdx.x * 128;
  float c[8][8];
#pragma unroll
  for (int i = 0; i < 8; i++)
#pragma unroll
    for (int j = 0; j < 8; j++) c[i][j] = 0.0f;

  for (int k0 = 0; k0 < K; k0 += 16) {
    __syncthreads();
#pragma unroll
    for (int p = 0; p < 2; p++) {
      int idx = t + 256 * p;           // 512 float4 for A tile
      int am = idx >> 2, kq = idx & 3;
      float4 av = *(const float4*)(A + (size_t)(m0 + am) * K + k0 + kq * 4);
      As[kq * 4 + 0][am] = av.x; As[kq * 4 + 1][am] = av.y;
      As[kq * 4 + 2][am] = av.z; As[kq * 4 + 3][am] = av.w;
      int bk = idx >> 5, bn = idx & 31;
      float4 bv = *(const float4*)(B + (size_t)(k0 + bk) * N + n0 + bn * 4);
      *(float4*)&Bs[bk][bn * 4] = bv;
    }
    __syncthreads();
#pragma unroll
    for (int kk = 0; kk < 16; kk++) {
      float4 a0 = *(const float4*)&As[kk][ty * 8];
      float4 a1 = *(const float4*)&As[kk][ty * 8 + 4];
      float4 b0 = *(const float4*)&Bs[kk][tx * 8];
      float4 b1 = *(const float4*)&Bs[kk][tx * 8 + 4];
      float a[8] = {a0.x, a0.y, a0.z, a0.w, a1.x, a1.y, a1.z, a1.w};
      float b[8] = {b0.x, b0.y, b0.z, b0.w, b1.x, b1.y, b1.z, b1.w};
#pragma unroll
      for (int i = 0; i < 8; i++)
#pragma unroll
        for (int j = 0; j < 8; j++) c[i][j] += a[i] * b[j];
    }
  }
#pragma unroll
  for (int i = 0; i < 8; i++) {
    size_t off = (size_t)(m0 + ty * 8 + i) * N + n0 + tx * 8;
    float4 v0 = make_float4(c[i][0], c[i][1], c[i][2], c[i][3]);
    float4 v1 = make_float4(c[i][4], c[i][5], c[i][6], c[i][7]);
    if (mode == 1) {
      float4 r0 = *(const float4*)(resid + off);
      float4 r1 = *(const float4*)(resid + off + 4);
      v0.x += r0.x; v0.y += r0.y; v0.z += r0.z; v0.w += r0.w;
      v1.x += r1.x; v1.y += r1.y; v1.z += r1.z; v1.w += r1.w;
    }
    *(float4*)(C + off) = v0;
    *(float4*)(C + off + 4) = v1;
  }
}

// ---------------------------------------------------------------------------
// RoPE in-place on q,k. f64 angles (matches numpy pow/cos rounding; upstream
// of router selection so precision matters).
// ---------------------------------------------------------------------------
__global__ __launch_bounds__(256) void rope_kernel(float* __restrict__ q,
                                                   float* __restrict__ k) {
  int gid = blockIdx.x * 256 + threadIdx.x;   // 4096 tok * 16 heads * 32 pairs
  int token = gid >> 9;
  int r = gid & 511;
  int hh = r >> 5, d = r & 31;
  int s = token & 1023;
  double inv = pow(10000.0, -(double)d / 32.0);
  double ang = (double)s * inv;
  float cs = (float)cos(ang), sn = (float)sin(ang);
  size_t base = (size_t)token * HDIM + hh * 64 + d;
  float q1 = q[base], q2 = q[base + 32];
  q[base] = q1 * cs - q2 * sn;
  q[base + 32] = q2 * cs + q1 * sn;
  float k1 = k[base], k2 = k[base + 32];
  k[base] = k1 * cs - k2 * sn;
  k[base + 32] = k2 * cs + k1 * sn;
}

// ---------------------------------------------------------------------------
// fp32 flash attention, causal, D=64. Block = (q-tile of 64 rows, one b*h).
// Online softmax; Q/K d-contig LDS, V stored d-major for vectorized PV.
// ---------------------------------------------------------------------------
__global__ __launch_bounds__(256) void attn_kernel(
    const float* __restrict__ q, const float* __restrict__ k,
    const float* __restrict__ v, float* __restrict__ ctx) {
  __shared__ __align__(16) float Qs[64][68];
  __shared__ __align__(16) float Ks[64][68];
  __shared__ __align__(16) float Vst[64][68];   // [d][key]
  __shared__ __align__(16) float Ps[64][68];
  __shared__ float mrow[64], lrow[64], arow[64];
  int t = threadIdx.x;
  int tx = t & 15, ty = t >> 4;
  int qt = blockIdx.x, bh = blockIdx.y;
  int b = bh >> 4, hh = bh & 15;
  const size_t base = (size_t)b * SEQ * HDIM + hh * 64;
#pragma unroll
  for (int p = 0; p < 4; p++) {
    int idx = t + 256 * p;
    int row = idx >> 4, d4 = idx & 15;
    *(float4*)&Qs[row][d4 * 4] =
        *(const float4*)(q + base + (size_t)(qt * 64 + row) * HDIM + d4 * 4);
  }
  float o[4][4] = {};
  if (t < 64) { mrow[t] = -1e30f; lrow[t] = 0.0f; }
  __syncthreads();

  for (int kt = 0; kt <= qt; kt++) {
#pragma unroll
    for (int p = 0; p < 4; p++) {
      int idx = t + 256 * p;
      int row = idx >> 4, d4 = idx & 15;
      *(float4*)&Ks[row][d4 * 4] =
          *(const float4*)(k + base + (size_t)(kt * 64 + row) * HDIM + d4 * 4);
      float4 vv =
          *(const float4*)(v + base + (size_t)(kt * 64 + row) * HDIM + d4 * 4);
      Vst[d4 * 4 + 0][row] = vv.x; Vst[d4 * 4 + 1][row] = vv.y;
      Vst[d4 * 4 + 2][row] = vv.z; Vst[d4 * 4 + 3][row] = vv.w;
    }
    __syncthreads();
    // scores: thread (tx,ty) -> q rows 4ty..+4, k cols tx+16*kj
    float s[4][4] = {};
#pragma unroll
    for (int d4 = 0; d4 < 16; d4++) {
      float4 qv[4], kv[4];
#pragma unroll
      for (int qi = 0; qi < 4; qi++) qv[qi] = *(const float4*)&Qs[ty * 4 + qi][d4 * 4];
#pragma unroll
      for (int kj = 0; kj < 4; kj++) kv[kj] = *(const float4*)&Ks[tx + 16 * kj][d4 * 4];
#pragma unroll
      for (int qi = 0; qi < 4; qi++)
#pragma unroll
        for (int kj = 0; kj < 4; kj++) s[qi][kj] += dot4(qv[qi], kv[kj]);
    }
#pragma unroll
    for (int qi = 0; qi < 4; qi++)
#pragma unroll
      for (int kj = 0; kj < 4; kj++) {
        int qg = qt * 64 + ty * 4 + qi;
        int kg = kt * 64 + tx + 16 * kj;
        float sc = s[qi][kj] * 0.125f;
        if (kg > qg) sc = -1e9f;
        Ps[ty * 4 + qi][tx + 16 * kj] = sc;
      }
    __syncthreads();
    {  // online softmax row stats: 4 threads per row
      int r = t >> 2, seg = t & 3;
      float mx = -1e30f;
#pragma unroll
      for (int j = 0; j < 16; j++) mx = fmaxf(mx, Ps[r][seg * 16 + j]);
      mx = fmaxf(mx, __shfl_xor(mx, 1));
      mx = fmaxf(mx, __shfl_xor(mx, 2));
      float mold = mrow[r];
      float mnew = fmaxf(mold, mx);
      float sum = 0.0f;
#pragma unroll
      for (int j = 0; j < 16; j++) {
        float pv = __expf(Ps[r][seg * 16 + j] - mnew);
        Ps[r][seg * 16 + j] = pv;
        sum += pv;
      }
      sum += __shfl_xor(sum, 1);
      sum += __shfl_xor(sum, 2);
      float alpha = __expf(mold - mnew);
      if (seg == 0) {
        mrow[r] = mnew;
        lrow[r] = lrow[r] * alpha + sum;
        arow[r] = alpha;
      }
    }
    __syncthreads();
#pragma unroll
    for (int qi = 0; qi < 4; qi++) {
      float al = arow[ty * 4 + qi];
#pragma unroll
      for (int di = 0; di < 4; di++) o[qi][di] *= al;
    }
#pragma unroll
    for (int kc = 0; kc < 16; kc++) {
      float4 pv[4], vv[4];
#pragma unroll
      for (int qi = 0; qi < 4; qi++) pv[qi] = *(const float4*)&Ps[ty * 4 + qi][kc * 4];
#pragma unroll
      for (int di = 0; di < 4; di++) vv[di] = *(const float4*)&Vst[tx + 16 * di][kc * 4];
#pragma unroll
      for (int qi = 0; qi < 4; qi++)
#pragma unroll
        for (int di = 0; di < 4; di++) o[qi][di] += dot4(pv[qi], vv[di]);
    }
    __syncthreads();
  }
#pragma unroll
  for (int qi = 0; qi < 4; qi++) {
    float linv = 1.0f / lrow[ty * 4 + qi];
#pragma unroll
    for (int di = 0; di < 4; di++)
      ctx[base + (size_t)(qt * 64 + ty * 4 + qi) * HDIM + tx + 16 * di] =
          o[qi][di] * linv;
  }
}

// ---------------------------------------------------------------------------
// Router: wave per token (16 tokens/wave), fp32 logits -> softmax -> top2.
// Emits gates (dense 4096x8, zeros elsewhere), topk idx, expert counts, P sums.
// ---------------------------------------------------------------------------
__global__ __launch_bounds__(256) void router_kernel(
    const float* __restrict__ xn, const float* __restrict__ wr,
    float* __restrict__ gates, int* __restrict__ topk,
    int* __restrict__ cnt, float* __restrict__ pacc) {
  int wid = threadIdx.x >> 6, lane = threadIdx.x & 63;
  float localP[8] = {};
  int localC[8] = {};
  for (int i = 0; i < 16; i++) {
    int t = blockIdx.x * 64 + wid * 16 + i;
    const float* xr = xn + (size_t)t * HDIM;
    float p[8] = {};
    for (int h = lane; h < HDIM; h += 64) {
      float xv = xr[h];
      const float* wrow = wr + h * 8;
#pragma unroll
      for (int e = 0; e < 8; e++) p[e] += xv * wrow[e];
    }
#pragma unroll
    for (int e = 0; e < 8; e++)
#pragma unroll
      for (int off = 32; off; off >>= 1) p[e] += __shfl_xor(p[e], off);
    if (lane == 0) {
      float m = p[0];
#pragma unroll
      for (int e = 1; e < 8; e++) m = fmaxf(m, p[e]);
      float s = 0.0f;
#pragma unroll
      for (int e = 0; e < 8; e++) { p[e] = expf(p[e] - m); s += p[e]; }
      float invs = 1.0f / s;
#pragma unroll
      for (int e = 0; e < 8; e++) p[e] *= invs;
      int i1 = 0; float b1 = p[0];
#pragma unroll
      for (int e = 1; e < 8; e++) if (p[e] > b1) { b1 = p[e]; i1 = e; }   // ties: lowest idx
      int i2 = -1; float b2 = -1.0f;
#pragma unroll
      for (int e = 0; e < 8; e++) if (e != i1 && p[e] > b2) { b2 = p[e]; i2 = e; }
      float gden = 1.0f / (b1 + b2);
#pragma unroll
      for (int e = 0; e < 8; e++)
        gates[(size_t)t * 8 + e] = (e == i1) ? b1 * gden : ((e == i2) ? b2 * gden : 0.0f);
      topk[t * 2] = i1; topk[t * 2 + 1] = i2;
      localC[i1]++; localC[i2]++;
#pragma unroll
      for (int e = 0; e < 8; e++) localP[e] += p[e];
    }
  }
  if (lane == 0) {
#pragma unroll
    for (int e = 0; e < 8; e++) {
      atomicAdd(&cnt[e], localC[e]);
      atomicAdd(&pacc[e], localP[e]);
    }
  }
}

__global__ void init_meta_kernel(int* cnt, int* fill, float* pacc) {
  int t = threadIdx.x;
  if (t < 8) { cnt[t] = 0; fill[t] = 0; pacc[t] = 0.0f; }
}

__global__ void build_schedule_kernel(const int* __restrict__ cnt,
                                      int* __restrict__ offs,
                                      int4* __restrict__ sched) {
  int off = 0, idx = 0;
  for (int e = 0; e < 8; e++) {
    offs[e] = off;
    int c = cnt[e];
    for (int r = 0; r < c; r += 128) {
      sched[idx] = make_int4(e, off + r, (c - r) < 128 ? (c - r) : 128, 0);
      idx++;
    }
    off += c;
  }
  offs[8] = off;
  for (; idx < MAXTILE; idx++) sched[idx] = make_int4(-1, 0, 0, 0);
}

__global__ __launch_bounds__(256) void scatter_kernel(
    const int* __restrict__ topk, const int* __restrict__ offs,
    int* __restrict__ fill, int* __restrict__ tlist) {
  int t = blockIdx.x * 256 + threadIdx.x;
  int i1 = topk[t * 2], i2 = topk[t * 2 + 1];
  int s1 = atomicAdd(&fill[i1], 1);
  tlist[offs[i1] + s1] = t;
  int s2 = atomicAdd(&fill[i2], 1);
  tlist[offs[i2] + s2] = t;
}

__global__ void aux_kernel(const int* __restrict__ cnt,
                           const float* __restrict__ pacc,
                           float* __restrict__ dout) {
  float a = 0.0f;
  for (int e = 0; e < 8; e++)
    a += ((float)cnt[e] / (NTOK * 2.0f)) * (pacc[e] / (float)NTOK);
  dout[(size_t)NTOK * HDIM] = 8.0f * a;
}

// ---------------------------------------------------------------------------
// Transpose + fp32->bf16 cast: out[c*R + r] = bf16(in[r*C + c]) per expert.
// ---------------------------------------------------------------------------
__global__ void transcast_kernel(const float* __restrict__ in,
                                 u16* __restrict__ out, int R, int C) {
  __shared__ float tile[32][33];
  size_t eo = (size_t)blockIdx.z * R * C;
  int c0 = blockIdx.x * 32, r0 = blockIdx.y * 32;
  int tx = threadIdx.x, ty = threadIdx.y;
#pragma unroll
  for (int i = 0; i < 4; i++)
    tile[ty + 8 * i][tx] = in[eo + (size_t)(r0 + ty + 8 * i) * C + c0 + tx];
  __syncthreads();
#pragma unroll
  for (int i = 0; i < 4; i++)
    out[eo + (size_t)(c0 + ty + 8 * i) * R + r0 + tx] = f2bf(tile[tx][ty + 8 * i]);
}

// ---------------------------------------------------------------------------
// bf16 MFMA GEMM over routed token tiles. MODE 0: h1 = gelu(xn2b @ w1[e]),
// A gathered via token list, K=1024, N=4096. MODE 1: d_out += gate * (h1 @
// w2[e]), A contiguous slots, K=4096, N=1024, scatter via atomicAdd.
// 128x128 tile, BK=64, 4 waves, each wave 4x4 grid of 16x16x32 MFMAs.
// ---------------------------------------------------------------------------
template <int MODE>
__global__ __launch_bounds__(256) void moe_gemm_kernel(
    const u16* __restrict__ Abase, const u16* __restrict__ Bbase,
    const int* __restrict__ tlist, const float* __restrict__ gates,
    u16* __restrict__ h1out, float* __restrict__ dout,
    const int4* __restrict__ sched) {
  int4 sc = sched[blockIdx.y];
  int e = sc.x;
  if (e < 0) return;
  int gslot0 = sc.y, nrows = sc.z;
  const int K = (MODE == 0) ? HDIM : FF;
  int n0 = blockIdx.x * 128;
  const u16* Bp = Bbase + (size_t)e * FF * HDIM;   // per-expert stride 4M elems
  __shared__ __align__(16) u16 As[128][72];
  __shared__ __align__(16) u16 Bs[128][72];
  int t = threadIdx.x, lane = t & 63, wid = t >> 6;
  int wm = wid & 1, wn = wid >> 1;
  int frow = lane & 15, fq = lane >> 4;
  f32x4 acc[4][4];
#pragma unroll
  for (int i = 0; i < 4; i++)
#pragma unroll
    for (int j = 0; j < 4; j++)
#pragma unroll
      for (int r = 0; r < 4; r++) acc[i][j][r] = 0.0f;

  int arow_idx[4];
#pragma unroll
  for (int p = 0; p < 4; p++) {
    int row = (t + 256 * p) >> 3;
    if (MODE == 0)
      arow_idx[p] = (row < nrows) ? tlist[gslot0 + row] : -1;
    else
      arow_idx[p] = (row < nrows) ? (gslot0 + row) : -1;
  }

  for (int k0 = 0; k0 < K; k0 += 64) {
    __syncthreads();
#pragma unroll
    for (int p = 0; p < 4; p++) {
      int idx = t + 256 * p;
      int row = idx >> 3, ch = idx & 7;
      uint4 av = make_uint4(0u, 0u, 0u, 0u);
      if (arow_idx[p] >= 0)
        av = *(const uint4*)(Abase + (size_t)arow_idx[p] * K + k0 + ch * 8);
      *(uint4*)&As[row][ch * 8] = av;
      uint4 bv = *(const uint4*)(Bp + (size_t)(n0 + row) * K + k0 + ch * 8);
      *(uint4*)&Bs[row][ch * 8] = bv;
    }
    __syncthreads();
#pragma unroll
    for (int c = 0; c < 2; c++) {
      bf16x8 af[4], bfr[4];
#pragma unroll
      for (int i = 0; i < 4; i++)
        af[i] = *(const bf16x8*)&As[wm * 64 + i * 16 + frow][c * 32 + fq * 8];
#pragma unroll
      for (int j = 0; j < 4; j++)
        bfr[j] = *(const bf16x8*)&Bs[wn * 64 + j * 16 + frow][c * 32 + fq * 8];
#pragma unroll
      for (int i = 0; i < 4; i++)
#pragma unroll
        for (int j = 0; j < 4; j++)
          acc[i][j] = __builtin_amdgcn_mfma_f32_16x16x32_bf16(af[i], bfr[j],
                                                              acc[i][j], 0, 0, 0);
    }
  }
  // epilogue: C/D layout col = lane&15, row = 4*(lane>>4) + reg  [m89/m91]
#pragma unroll
  for (int i = 0; i < 4; i++)
#pragma unroll
    for (int j = 0; j < 4; j++) {
      int col = n0 + wn * 64 + j * 16 + frow;
#pragma unroll
      for (int r = 0; r < 4; r++) {
        int lr = wm * 64 + i * 16 + fq * 4 + r;
        if (lr < nrows) {
          float val = acc[i][j][r];
          if (MODE == 0) {
            h1out[(size_t)(gslot0 + lr) * FF + col] = f2bf(gelu_f(val));
          } else {
            int tok = tlist[gslot0 + lr];
            float g = gates[(size_t)tok * 8 + e];
            atomicAdd(&dout[(size_t)tok * HDIM + col], g * val);
          }
        }
      }
    }
}

// ---------------------------------------------------------------------------
extern "C" void kernel_launch(void* const* d_in, const int* in_sizes, int n_in,
                              void* d_out, int out_size, void* d_ws,
                              size_t ws_size, hipStream_t stream) {
  const float* x        = (const float*)d_in[0];
  const float* g_attn   = (const float*)d_in[1];
  const float* wq       = (const float*)d_in[2];
  const float* wk       = (const float*)d_in[3];
  const float* wv       = (const float*)d_in[4];
  const float* wo       = (const float*)d_in[5];
  const float* g_ffn    = (const float*)d_in[6];
  const float* w_router = (const float*)d_in[7];
  const float* w1       = (const float*)d_in[8];
  const float* w2       = (const float*)d_in[9];
  float* out = (float*)d_out;
  char* ws = (char*)d_ws;
  const size_t MB = 1048576;

  // ws layout (~233 MB, with temporal overlays):
  float* xn1  = (float*)(ws + 0);          // 16MB, dead after WO gemm
  float* qb   = (float*)(ws + 16 * MB);    // 16MB
  float* kb   = (float*)(ws + 32 * MB);    // 16MB
  float* vb   = (float*)(ws + 48 * MB);    // 16MB
  u16*   h1   = (u16*)(ws + 0);            // 64MB, overlays xn1/q/k/v (dead)
  float* ctxb = (float*)(ws + 64 * MB);    // 16MB, dead after WO gemm
  float* gates = (float*)(ws + 64 * MB);   // 128KB, overlays dead ctx
  char* meta = ws + 64 * MB + 256 * 1024;  // overlays dead ctx
  int4* sched = (int4*)meta;               // 72*16B
  int* cnt  = (int*)(meta + 2048);         // 8
  int* fill = cnt + 8;                     // 8
  int* offs = fill + 8;                    // 9
  float* pacc = (float*)(offs + 16);       // 8 (aligned enough)
  int* topk  = (int*)(pacc + 8);           // 8192
  int* tlist = topk + 8192;                // 8192
  float* xn2f = (float*)(ws + 80 * MB);    // 16MB
  u16*   xn2b = (u16*)(ws + 96 * MB);      // 8MB
  u16*   w1T  = (u16*)(ws + 104 * MB);     // 64MB  (per-expert [n][k])
  u16*   w2T  = (u16*)(ws + 168 * MB);     // 64MB  (per-expert [n][k])

  // 1. xn1 = rmsnorm(x, g_attn)   [fp32 only]
  rmsnorm_kernel<<<NTOK, 256, 0, stream>>>(x, g_attn, xn1, nullptr, 0);
  // 2-4. q,k,v projections (fp32)
  sgemm_kernel<<<dim3(8, 32), 256, 0, stream>>>(xn1, wq, qb, nullptr, NTOK, HDIM, HDIM, 0);
  sgemm_kernel<<<dim3(8, 32), 256, 0, stream>>>(xn1, wk, kb, nullptr, NTOK, HDIM, HDIM, 0);
  sgemm_kernel<<<dim3(8, 32), 256, 0, stream>>>(xn1, wv, vb, nullptr, NTOK, HDIM, HDIM, 0);
  // 5. rope on q,k
  rope_kernel<<<8192, 256, 0, stream>>>(qb, kb);
  // 6. attention
  attn_kernel<<<dim3(16, 64), 256, 0, stream>>>(qb, kb, vb, ctxb);
  // 7. d_out = x + ctx @ wo   (= x2)
  sgemm_kernel<<<dim3(8, 32), 256, 0, stream>>>(ctxb, wo, out, x, NTOK, HDIM, HDIM, 1);
  // 8. xn2 = rmsnorm(x2, g_ffn)  fp32 + bf16
  rmsnorm_kernel<<<NTOK, 256, 0, stream>>>(out, g_ffn, xn2f, xn2b, 1);
  // 9. routing
  init_meta_kernel<<<1, 64, 0, stream>>>(cnt, fill, pacc);
  router_kernel<<<64, 256, 0, stream>>>(xn2f, w_router, gates, topk, cnt, pacc);
  build_schedule_kernel<<<1, 1, 0, stream>>>(cnt, offs, sched);
  scatter_kernel<<<16, 256, 0, stream>>>(topk, offs, fill, tlist);
  // 10. weight cast+transpose to bf16 [n][k]
  transcast_kernel<<<dim3(128, 32, 8), dim3(32, 8), 0, stream>>>(w1, w1T, HDIM, FF);
  transcast_kernel<<<dim3(32, 128, 8), dim3(32, 8), 0, stream>>>(w2, w2T, FF, HDIM);
  // 11. expert GEMMs (bf16 MFMA, routed)
  moe_gemm_kernel<0><<<dim3(FF / 128, MAXTILE), 256, 0, stream>>>(
      xn2b, w1T, tlist, gates, h1, out, sched);
  moe_gemm_kernel<1><<<dim3(HDIM / 128, MAXTILE), 256, 0, stream>>>(
      h1, w2T, tlist, gates, nullptr, out, sched);
  // 12. aux loss scalar
  aux_kernel<<<1, 1, 0, stream>>>(cnt, pacc, out);
}

// Round 2
// 1812.928 us; speedup vs baseline: 1.1728x; 1.1728x over previous
//
#include <hip/hip_runtime.h>
#include <cstdint>
#include <cstddef>

// ---------------------------------------------------------------------------
// JetFFNMoEBlock. Precision: router-feeding path must stay fp32-accurate
// (logit gaps ~1e-4; flips cost ~0.2 absmax vs 0.1175 threshold). Projection
// GEMMs use split-bf16 MFMA (3-term hi/lo: error ~2^-18 rel, fp32-class).
// Attention stays fp32 VALU (latency-bound, only ~9 GF). Expert GEMMs are
// plain bf16 MFMA (post-selection, additive ~0.03 absmax, safe).
// ---------------------------------------------------------------------------

typedef unsigned short u16;
typedef __attribute__((ext_vector_type(8))) short bf16x8;
typedef __attribute__((ext_vector_type(4))) float f32x4;

#define HDIM 1024
#define NTOK 4096
#define SEQ  1024
#define FF 4096
#define MAXTILE 72

__device__ __forceinline__ u16 f2bf(float f) {
  uint32_t u = __float_as_uint(f);
  u = (u + 0x7FFFu + ((u >> 16) & 1u)) >> 16;   // RNE
  return (u16)u;
}
__device__ __forceinline__ float bf2f(u16 h) {
  return __uint_as_float((uint32_t)h << 16);
}

__device__ __forceinline__ float gelu_f(float x) {
  float u = 0.7978845608028654f * (x + 0.044715f * x * x * x);
  float ex = __expf(2.0f * u);
  return 0.5f * x * (1.0f + (1.0f - 2.0f / (ex + 1.0f)));
}

__device__ __forceinline__ float dot4(float4 a, float4 b) {
  return a.x * b.x + a.y * b.y + a.z * b.z + a.w * b.w;
}

// ---------------------------------------------------------------------------
// RoPE cos/sin table [1024 pos][32 d], f64-accurate (matches numpy rounding).
// ---------------------------------------------------------------------------
__global__ void ropetab_kernel(float2* __restrict__ rt) {
  int idx = blockIdx.x * 256 + threadIdx.x;   // 32768
  int s = idx >> 5, d = idx & 31;
  double inv = pow(10000.0, -(double)d / 32.0);
  double ang = (double)s * inv;
  rt[idx] = make_float2((float)cos(ang), (float)sin(ang));
}

// ---------------------------------------------------------------------------
// RMSNorm: one block per row of 1024. Optional fp32 / bf16-hi / bf16-lo outs.
// ---------------------------------------------------------------------------
__global__ __launch_bounds__(256) void rmsnorm_kernel(
    const float* __restrict__ x, const float* __restrict__ g,
    float* __restrict__ outf, u16* __restrict__ outhi, u16* __restrict__ outlo) {
  int row = blockIdx.x;
  int t = threadIdx.x;
  const float4 xv = ((const float4*)(x + (size_t)row * HDIM))[t];
  float ss = xv.x * xv.x + xv.y * xv.y + xv.z * xv.z + xv.w * xv.w;
#pragma unroll
  for (int off = 32; off; off >>= 1) ss += __shfl_xor(ss, off);
  __shared__ float wsum[4];
  if ((t & 63) == 0) wsum[t >> 6] = ss;
  __syncthreads();
  float tot = wsum[0] + wsum[1] + wsum[2] + wsum[3];
  float scale = 1.0f / sqrtf(tot * (1.0f / HDIM) + 1e-5f);
  const float4 gv = ((const float4*)g)[t];
  float o[4] = {xv.x * scale * gv.x, xv.y * scale * gv.y,
                xv.z * scale * gv.z, xv.w * scale * gv.w};
  if (outf) *(float4*)(outf + (size_t)row * HDIM + t * 4) = make_float4(o[0], o[1], o[2], o[3]);
  u16 h[4];
#pragma unroll
  for (int i = 0; i < 4; i++) h[i] = f2bf(o[i]);
  if (outhi) {
    uint2 p;
    p.x = (uint32_t)h[0] | ((uint32_t)h[1] << 16);
    p.y = (uint32_t)h[2] | ((uint32_t)h[3] << 16);
    ((uint2*)(outhi + (size_t)row * HDIM))[t] = p;
  }
  if (outlo) {
    uint2 p;
    u16 lo[4];
#pragma unroll
    for (int i = 0; i < 4; i++) lo[i] = f2bf(o[i] - bf2f(h[i]));
    p.x = (uint32_t)lo[0] | ((uint32_t)lo[1] << 16);
    p.y = (uint32_t)lo[2] | ((uint32_t)lo[3] << 16);
    ((uint2*)(outlo + (size_t)row * HDIM))[t] = p;
  }
}

// ---------------------------------------------------------------------------
// Weight transpose+cast fp32 [R][C] -> bf16 hi/lo [C][R]  (K-contiguous B^T).
// ---------------------------------------------------------------------------
__global__ void transcast_hilo_kernel(const float* __restrict__ in,
                                      u16* __restrict__ ohi, u16* __restrict__ olo,
                                      int R, int C) {
  __shared__ float tile[32][33];
  int c0 = blockIdx.x * 32, r0 = blockIdx.y * 32;
  int tx = threadIdx.x, ty = threadIdx.y;
#pragma unroll
  for (int i = 0; i < 4; i++)
    tile[ty + 8 * i][tx] = in[(size_t)(r0 + ty + 8 * i) * C + c0 + tx];
  __syncthreads();
#pragma unroll
  for (int i = 0; i < 4; i++) {
    float vv = tile[tx][ty + 8 * i];
    u16 h = f2bf(vv);
    size_t oidx = (size_t)(c0 + ty + 8 * i) * R + r0 + tx;
    ohi[oidx] = h;
    olo[oidx] = f2bf(vv - bf2f(h));
  }
}

// single-bf16 version (MoE weights), per-expert via blockIdx.z
__global__ void transcast_kernel(const float* __restrict__ in,
                                 u16* __restrict__ out, int R, int C) {
  __shared__ float tile[32][33];
  size_t eo = (size_t)blockIdx.z * R * C;
  int c0 = blockIdx.x * 32, r0 = blockIdx.y * 32;
  int tx = threadIdx.x, ty = threadIdx.y;
#pragma unroll
  for (int i = 0; i < 4; i++)
    tile[ty + 8 * i][tx] = in[eo + (size_t)(r0 + ty + 8 * i) * C + c0 + tx];
  __syncthreads();
#pragma unroll
  for (int i = 0; i < 4; i++)
    out[eo + (size_t)(c0 + ty + 8 * i) * R + r0 + tx] = f2bf(tile[tx][ty + 8 * i]);
}

// ---------------------------------------------------------------------------
// Split-bf16 MFMA GEMM main loop: acc += AhiBhi + AloBhi + AhiBlo over K=1024.
// 128x128 tile, BK=64, 4 waves, 4x4 of 16x16x32 MFMAs per wave.
// ---------------------------------------------------------------------------
__device__ __forceinline__ void g3_loop(
    const u16* __restrict__ Ahi, const u16* __restrict__ Alo,
    const u16* __restrict__ BH, const u16* __restrict__ BL,
    int m0, int n0, u16 (&As)[128][72], u16 (&Bs)[128][72],
    f32x4 (&acc)[4][4]) {
  const int K = HDIM;
  int t = threadIdx.x, lane = t & 63, wid = t >> 6;
  int wm = wid & 1, wn = wid >> 1;
  int frow = lane & 15, fq = lane >> 4;
  const u16* Aps[3] = {Ahi, Alo, Ahi};
  const u16* Bps[3] = {BH, BH, BL};
#pragma unroll 1
  for (int p = 0; p < 3; p++) {
    const u16* Ap = Aps[p];
    const u16* Bp = Bps[p];
    for (int k0 = 0; k0 < K; k0 += 64) {
      __syncthreads();
#pragma unroll
      for (int pp = 0; pp < 4; pp++) {
        int idx = t + 256 * pp;
        int row = idx >> 3, ch = idx & 7;
        *(uint4*)&As[row][ch * 8] =
            *(const uint4*)(Ap + (size_t)(m0 + row) * K + k0 + ch * 8);
        *(uint4*)&Bs[row][ch * 8] =
            *(const uint4*)(Bp + (size_t)(n0 + row) * K + k0 + ch * 8);
      }
      __syncthreads();
#pragma unroll
      for (int c = 0; c < 2; c++) {
        bf16x8 af[4], bfr[4];
#pragma unroll
        for (int i = 0; i < 4; i++)
          af[i] = *(const bf16x8*)&As[wm * 64 + i * 16 + frow][c * 32 + fq * 8];
#pragma unroll
        for (int j = 0; j < 4; j++)
          bfr[j] = *(const bf16x8*)&Bs[wn * 64 + j * 16 + frow][c * 32 + fq * 8];
#pragma unroll
        for (int i = 0; i < 4; i++)
#pragma unroll
          for (int j = 0; j < 4; j++)
            acc[i][j] = __builtin_amdgcn_mfma_f32_16x16x32_bf16(
                af[i], bfr[j], acc[i][j], 0, 0, 0);
      }
    }
  }
}

// QKV fused: grid.x = 24 n-tiles (0-7 q, 8-15 k, 16-23 v); rope fused for q,k.
__global__ __launch_bounds__(256) void gemm3_qkv_kernel(
    const u16* __restrict__ Ahi, const u16* __restrict__ Alo,
    const u16* __restrict__ WqH, const u16* __restrict__ WqL,
    const u16* __restrict__ WkH, const u16* __restrict__ WkL,
    const u16* __restrict__ WvH, const u16* __restrict__ WvL,
    float* __restrict__ qb, float* __restrict__ kb, float* __restrict__ vb,
    const float2* __restrict__ rtab) {
  __shared__ __align__(16) u16 As[128][72];
  __shared__ __align__(16) u16 Bs[128][72];
  int cls = blockIdx.x >> 3;
  int n0 = (blockIdx.x & 7) * 128, m0 = blockIdx.y * 128;
  const u16* BH = cls == 0 ? WqH : (cls == 1 ? WkH : WvH);
  const u16* BL = cls == 0 ? WqL : (cls == 1 ? WkL : WvL);
  float* outp = cls == 0 ? qb : (cls == 1 ? kb : vb);
  f32x4 acc[4][4];
#pragma unroll
  for (int i = 0; i < 4; i++)
#pragma unroll
    for (int j = 0; j < 4; j++)
#pragma unroll
      for (int r = 0; r < 4; r++) acc[i][j][r] = 0.0f;
  g3_loop(Ahi, Alo, BH, BL, m0, n0, As, Bs, acc);
  int t = threadIdx.x, lane = t & 63, wid = t >> 6;
  int wm = wid & 1, wn = wid >> 1, frow = lane & 15, fq = lane >> 4;
#pragma unroll
  for (int i = 0; i < 4; i++)
#pragma unroll
    for (int r = 0; r < 4; r++) {
      int row = m0 + wm * 64 + i * 16 + fq * 4 + r;
      int s = row & (SEQ - 1);
      if (cls < 2) {
#pragma unroll
        for (int j = 0; j < 2; j++) {          // pair (d, d+32) = (j, j+2)
          int d = j * 16 + frow;               // in-head dim, < 32
          int col = n0 + wn * 64 + j * 16 + frow;
          float2 cs = rtab[s * 32 + d];
          float a = acc[i][j][r], b2 = acc[i][j + 2][r];
          outp[(size_t)row * HDIM + col]      = a * cs.x - b2 * cs.y;
          outp[(size_t)row * HDIM + col + 32] = b2 * cs.x + a * cs.y;
        }
      } else {
#pragma unroll
        for (int j = 0; j < 4; j++)
          outp[(size_t)row * HDIM + n0 + wn * 64 + j * 16 + frow] = acc[i][j][r];
      }
    }
}

// WO: out = ctx @ wo + x  (fp32 out = x2, the residual stream)
__global__ __launch_bounds__(256) void gemm3_wo_kernel(
    const u16* __restrict__ Ahi, const u16* __restrict__ Alo,
    const u16* __restrict__ WH, const u16* __restrict__ WL,
    const float* __restrict__ resid, float* __restrict__ outp) {
  __shared__ __align__(16) u16 As[128][72];
  __shared__ __align__(16) u16 Bs[128][72];
  int n0 = blockIdx.x * 128, m0 = blockIdx.y * 128;
  f32x4 acc[4][4];
#pragma unroll
  for (int i = 0; i < 4; i++)
#pragma unroll
    for (int j = 0; j < 4; j++)
#pragma unroll
      for (int r = 0; r < 4; r++) acc[i][j][r] = 0.0f;
  g3_loop(Ahi, Alo, WH, WL, m0, n0, As, Bs, acc);
  int t = threadIdx.x, lane = t & 63, wid = t >> 6;
  int wm = wid & 1, wn = wid >> 1, frow = lane & 15, fq = lane >> 4;
#pragma unroll
  for (int i = 0; i < 4; i++)
#pragma unroll
    for (int r = 0; r < 4; r++) {
      int row = m0 + wm * 64 + i * 16 + fq * 4 + r;
#pragma unroll
      for (int j = 0; j < 4; j++) {
        size_t off = (size_t)row * HDIM + n0 + wn * 64 + j * 16 + frow;
        outp[off] = acc[i][j][r] + resid[off];
      }
    }
}

// ---------------------------------------------------------------------------
// fp32 flash attention, causal, D=64, q-tile 64. m/l/alpha in registers
// (shuffle stats over 16 tx-lanes); P reuses the Ks LDS buffer; K/V tile
// prefetched into registers one iteration ahead. LDS 52 KB -> 3 blocks/CU.
// Emits ctx as bf16 hi/lo for the split WO GEMM.
// ---------------------------------------------------------------------------
__global__ __launch_bounds__(256) void attn_kernel(
    const float* __restrict__ q, const float* __restrict__ k,
    const float* __restrict__ v, u16* __restrict__ ctxhi,
    u16* __restrict__ ctxlo) {
  __shared__ __align__(16) float Qs[64][68];
  __shared__ __align__(16) float Ks[64][68];   // K tile, then P after QK
  __shared__ __align__(16) float Vst[64][68];  // [d][key]
  int t = threadIdx.x;
  int tx = t & 15, ty = t >> 4;
  int qt = blockIdx.x, bh = blockIdx.y;
  int b = bh >> 4, hh = bh & 15;
  const size_t base = (size_t)b * SEQ * HDIM + hh * 64;
#pragma unroll
  for (int p = 0; p < 4; p++) {
    int idx = t + 256 * p;
    int row = idx >> 4, d4 = idx & 15;
    *(float4*)&Qs[row][d4 * 4] =
        *(const float4*)(q + base + (size_t)(qt * 64 + row) * HDIM + d4 * 4);
  }
  float m[4], l[4], o[4][4];
#pragma unroll
  for (int qi = 0; qi < 4; qi++) {
    m[qi] = -1e30f; l[qi] = 0.0f;
#pragma unroll
    for (int di = 0; di < 4; di++) o[qi][di] = 0.0f;
  }
  float4 kreg[4], vreg[4];
  {
#pragma unroll
    for (int p = 0; p < 4; p++) {
      int idx = t + 256 * p;
      int row = idx >> 4, d4 = idx & 15;
      kreg[p] = *(const float4*)(k + base + (size_t)row * HDIM + d4 * 4);
      vreg[p] = *(const float4*)(v + base + (size_t)row * HDIM + d4 * 4);
    }
  }
  for (int kt = 0; kt <= qt; kt++) {
    __syncthreads();   // prev PV reads (and initial Qs write) complete
#pragma unroll
    for (int p = 0; p < 4; p++) {
      int idx = t + 256 * p;
      int row = idx >> 4, d4 = idx & 15;
      *(float4*)&Ks[row][d4 * 4] = kreg[p];
      Vst[d4 * 4 + 0][row] = vreg[p].x; Vst[d4 * 4 + 1][row] = vreg[p].y;
      Vst[d4 * 4 + 2][row] = vreg[p].z; Vst[d4 * 4 + 3][row] = vreg[p].w;
    }
    __syncthreads();
    if (kt < qt) {   // prefetch next tile (latency hidden across QK+PV)
#pragma unroll
      for (int p = 0; p < 4; p++) {
        int idx = t + 256 * p;
        int row = idx >> 4, d4 = idx & 15;
        kreg[p] = *(const float4*)(k + base + (size_t)((kt + 1) * 64 + row) * HDIM + d4 * 4);
        vreg[p] = *(const float4*)(v + base + (size_t)((kt + 1) * 64 + row) * HDIM + d4 * 4);
      }
    }
    // QK^T: thread (tx,ty) -> q rows ty*4+qi, k cols tx+16*kj
    float s[4][4] = {};
#pragma unroll
    for (int d4 = 0; d4 < 16; d4++) {
      float4 qv[4], kv[4];
#pragma unroll
      for (int qi = 0; qi < 4; qi++) qv[qi] = *(const float4*)&Qs[ty * 4 + qi][d4 * 4];
#pragma unroll
      for (int kj = 0; kj < 4; kj++) kv[kj] = *(const float4*)&Ks[tx + 16 * kj][d4 * 4];
#pragma unroll
      for (int qi = 0; qi < 4; qi++)
#pragma unroll
        for (int kj = 0; kj < 4; kj++) s[qi][kj] += dot4(qv[qi], kv[kj]);
    }
    float alpha[4];
#pragma unroll
    for (int qi = 0; qi < 4; qi++) {
      int qg = qt * 64 + ty * 4 + qi;
#pragma unroll
      for (int kj = 0; kj < 4; kj++) {
        int kg = kt * 64 + tx + 16 * kj;
        float sc = s[qi][kj] * 0.125f;
        if (kg > qg) sc = -1e9f;
        s[qi][kj] = sc;
      }
      float mx = fmaxf(fmaxf(s[qi][0], s[qi][1]), fmaxf(s[qi][2], s[qi][3]));
      mx = fmaxf(mx, __shfl_xor(mx, 1));
      mx = fmaxf(mx, __shfl_xor(mx, 2));
      mx = fmaxf(mx, __shfl_xor(mx, 4));
      mx = fmaxf(mx, __shfl_xor(mx, 8));
      float mn = fmaxf(m[qi], mx);
      float sum = 0.0f;
#pragma unroll
      for (int kj = 0; kj < 4; kj++) {
        s[qi][kj] = __expf(s[qi][kj] - mn);
        sum += s[qi][kj];
      }
      sum += __shfl_xor(sum, 1);
      sum += __shfl_xor(sum, 2);
      sum += __shfl_xor(sum, 4);
      sum += __shfl_xor(sum, 8);
      alpha[qi] = __expf(m[qi] - mn);
      l[qi] = l[qi] * alpha[qi] + sum;
      m[qi] = mn;
#pragma unroll
      for (int di = 0; di < 4; di++) o[qi][di] *= alpha[qi];
    }
    __syncthreads();   // all QK reads of Ks done
#pragma unroll
    for (int qi = 0; qi < 4; qi++)
#pragma unroll
      for (int kj = 0; kj < 4; kj++) Ks[ty * 4 + qi][tx + 16 * kj] = s[qi][kj];
    __syncthreads();
    // PV: o[qi][di] += sum_k P[q][k] * V[k][d],  d = tx+16*di
#pragma unroll
    for (int kc = 0; kc < 16; kc++) {
      float4 pv[4], vv[4];
#pragma unroll
      for (int qi = 0; qi < 4; qi++) pv[qi] = *(const float4*)&Ks[ty * 4 + qi][kc * 4];
#pragma unroll
      for (int di = 0; di < 4; di++) vv[di] = *(const float4*)&Vst[tx + 16 * di][kc * 4];
#pragma unroll
      for (int qi = 0; qi < 4; qi++)
#pragma unroll
        for (int di = 0; di < 4; di++) o[qi][di] += dot4(pv[qi], vv[di]);
    }
  }
#pragma unroll
  for (int qi = 0; qi < 4; qi++) {
    float linv = 1.0f / l[qi];
#pragma unroll
    for (int di = 0; di < 4; di++) {
      size_t addr = base + (size_t)(qt * 64 + ty * 4 + qi) * HDIM + tx + 16 * di;
      float vv = o[qi][di] * linv;
      u16 h = f2bf(vv);
      ctxhi[addr] = h;
      ctxlo[addr] = f2bf(vv - bf2f(h));
    }
  }
}

// ---------------------------------------------------------------------------
// Router (fp32, exact top-2 semantics) + schedule + scatter + aux. Unchanged.
// ---------------------------------------------------------------------------
__global__ __launch_bounds__(256) void router_kernel(
    const float* __restrict__ xn, const float* __restrict__ wr,
    float* __restrict__ gates, int* __restrict__ topk,
    int* __restrict__ cnt, float* __restrict__ pacc) {
  int wid = threadIdx.x >> 6, lane = threadIdx.x & 63;
  float localP[8] = {};
  int localC[8] = {};
  for (int i = 0; i < 16; i++) {
    int t = blockIdx.x * 64 + wid * 16 + i;
    const float* xr = xn + (size_t)t * HDIM;
    float p[8] = {};
    for (int h = lane; h < HDIM; h += 64) {
      float xv = xr[h];
      const float* wrow = wr + h * 8;
#pragma unroll
      for (int e = 0; e < 8; e++) p[e] += xv * wrow[e];
    }
#pragma unroll
    for (int e = 0; e < 8; e++)
#pragma unroll
      for (int off = 32; off; off >>= 1) p[e] += __shfl_xor(p[e], off);
    if (lane == 0) {
      float m = p[0];
#pragma unroll
      for (int e = 1; e < 8; e++) m = fmaxf(m, p[e]);
      float s = 0.0f;
#pragma unroll
      for (int e = 0; e < 8; e++) { p[e] = expf(p[e] - m); s += p[e]; }
      float invs = 1.0f / s;
#pragma unroll
      for (int e = 0; e < 8; e++) p[e] *= invs;
      int i1 = 0; float b1 = p[0];
#pragma unroll
      for (int e = 1; e < 8; e++) if (p[e] > b1) { b1 = p[e]; i1 = e; }
      int i2 = -1; float b2 = -1.0f;
#pragma unroll
      for (int e = 0; e < 8; e++) if (e != i1 && p[e] > b2) { b2 = p[e]; i2 = e; }
      float gden = 1.0f / (b1 + b2);
#pragma unroll
      for (int e = 0; e < 8; e++)
        gates[(size_t)t * 8 + e] = (e == i1) ? b1 * gden : ((e == i2) ? b2 * gden : 0.0f);
      topk[t * 2] = i1; topk[t * 2 + 1] = i2;
      localC[i1]++; localC[i2]++;
#pragma unroll
      for (int e = 0; e < 8; e++) localP[e] += p[e];
    }
  }
  if (lane == 0) {
#pragma unroll
    for (int e = 0; e < 8; e++) {
      atomicAdd(&cnt[e], localC[e]);
      atomicAdd(&pacc[e], localP[e]);
    }
  }
}

__global__ void init_meta_kernel(int* cnt, int* fill, float* pacc) {
  int t = threadIdx.x;
  if (t < 8) { cnt[t] = 0; fill[t] = 0; pacc[t] = 0.0f; }
}

__global__ void build_schedule_kernel(const int* __restrict__ cnt,
                                      int* __restrict__ offs,
                                      int4* __restrict__ sched) {
  int off = 0, idx = 0;
  for (int e = 0; e < 8; e++) {
    offs[e] = off;
    int c = cnt[e];
    for (int r = 0; r < c; r += 128) {
      sched[idx] = make_int4(e, off + r, (c - r) < 128 ? (c - r) : 128, 0);
      idx++;
    }
    off += c;
  }
  offs[8] = off;
  for (; idx < MAXTILE; idx++) sched[idx] = make_int4(-1, 0, 0, 0);
}

__global__ __launch_bounds__(256) void scatter_kernel(
    const int* __restrict__ topk, const int* __restrict__ offs,
    int* __restrict__ fill, int* __restrict__ tlist) {
  int t = blockIdx.x * 256 + threadIdx.x;
  int i1 = topk[t * 2], i2 = topk[t * 2 + 1];
  int s1 = atomicAdd(&fill[i1], 1);
  tlist[offs[i1] + s1] = t;
  int s2 = atomicAdd(&fill[i2], 1);
  tlist[offs[i2] + s2] = t;
}

__global__ void aux_kernel(const int* __restrict__ cnt,
                           const float* __restrict__ pacc,
                           float* __restrict__ dout) {
  float a = 0.0f;
  for (int e = 0; e < 8; e++)
    a += ((float)cnt[e] / (NTOK * 2.0f)) * (pacc[e] / (float)NTOK);
  dout[(size_t)NTOK * HDIM] = 8.0f * a;
}

// ---------------------------------------------------------------------------
// bf16 MFMA GEMM over routed token tiles (unchanged from R1, passing).
// ---------------------------------------------------------------------------
template <int MODE>
__global__ __launch_bounds__(256) void moe_gemm_kernel(
    const u16* __restrict__ Abase, const u16* __restrict__ Bbase,
    const int* __restrict__ tlist, const float* __restrict__ gates,
    u16* __restrict__ h1out, float* __restrict__ dout,
    const int4* __restrict__ sched) {
  int4 sc = sched[blockIdx.y];
  int e = sc.x;
  if (e < 0) return;
  int gslot0 = sc.y, nrows = sc.z;
  const int K = (MODE == 0) ? HDIM : FF;
  int n0 = blockIdx.x * 128;
  const u16* Bp = Bbase + (size_t)e * FF * HDIM;
  __shared__ __align__(16) u16 As[128][72];
  __shared__ __align__(16) u16 Bs[128][72];
  int t = threadIdx.x, lane = t & 63, wid = t >> 6;
  int wm = wid & 1, wn = wid >> 1;
  int frow = lane & 15, fq = lane >> 4;
  f32x4 acc[4][4];
#pragma unroll
  for (int i = 0; i < 4; i++)
#pragma unroll
    for (int j = 0; j < 4; j++)
#pragma unroll
      for (int r = 0; r < 4; r++) acc[i][j][r] = 0.0f;

  int arow_idx[4];
#pragma unroll
  for (int p = 0; p < 4; p++) {
    int row = (t + 256 * p) >> 3;
    if (MODE == 0)
      arow_idx[p] = (row < nrows) ? tlist[gslot0 + row] : -1;
    else
      arow_idx[p] = (row < nrows) ? (gslot0 + row) : -1;
  }

  for (int k0 = 0; k0 < K; k0 += 64) {
    __syncthreads();
#pragma unroll
    for (int p = 0; p < 4; p++) {
      int idx = t + 256 * p;
      int row = idx >> 3, ch = idx & 7;
      uint4 av = make_uint4(0u, 0u, 0u, 0u);
      if (arow_idx[p] >= 0)
        av = *(const uint4*)(Abase + (size_t)arow_idx[p] * K + k0 + ch * 8);
      *(uint4*)&As[row][ch * 8] = av;
      uint4 bv = *(const uint4*)(Bp + (size_t)(n0 + row) * K + k0 + ch * 8);
      *(uint4*)&Bs[row][ch * 8] = bv;
    }
    __syncthreads();
#pragma unroll
    for (int c = 0; c < 2; c++) {
      bf16x8 af[4], bfr[4];
#pragma unroll
      for (int i = 0; i < 4; i++)
        af[i] = *(const bf16x8*)&As[wm * 64 + i * 16 + frow][c * 32 + fq * 8];
#pragma unroll
      for (int j = 0; j < 4; j++)
        bfr[j] = *(const bf16x8*)&Bs[wn * 64 + j * 16 + frow][c * 32 + fq * 8];
#pragma unroll
      for (int i = 0; i < 4; i++)
#pragma unroll
        for (int j = 0; j < 4; j++)
          acc[i][j] = __builtin_amdgcn_mfma_f32_16x16x32_bf16(af[i], bfr[j],
                                                              acc[i][j], 0, 0, 0);
    }
  }
#pragma unroll
  for (int i = 0; i < 4; i++)
#pragma unroll
    for (int j = 0; j < 4; j++) {
      int col = n0 + wn * 64 + j * 16 + frow;
#pragma unroll
      for (int r = 0; r < 4; r++) {
        int lr = wm * 64 + i * 16 + fq * 4 + r;
        if (lr < nrows) {
          float val = acc[i][j][r];
          if (MODE == 0) {
            h1out[(size_t)(gslot0 + lr) * FF + col] = f2bf(gelu_f(val));
          } else {
            int tok = tlist[gslot0 + lr];
            float g = gates[(size_t)tok * 8 + e];
            atomicAdd(&dout[(size_t)tok * HDIM + col], g * val);
          }
        }
      }
    }
}

// ---------------------------------------------------------------------------
extern "C" void kernel_launch(void* const* d_in, const int* in_sizes, int n_in,
                              void* d_out, int out_size, void* d_ws,
                              size_t ws_size, hipStream_t stream) {
  const float* x        = (const float*)d_in[0];
  const float* g_attn   = (const float*)d_in[1];
  const float* wq       = (const float*)d_in[2];
  const float* wk       = (const float*)d_in[3];
  const float* wv       = (const float*)d_in[4];
  const float* wo       = (const float*)d_in[5];
  const float* g_ffn    = (const float*)d_in[6];
  const float* w_router = (const float*)d_in[7];
  const float* w1       = (const float*)d_in[8];
  const float* w2       = (const float*)d_in[9];
  float* out = (float*)d_out;
  char* ws = (char*)d_ws;
  const size_t MB = 1048576;

  // ws layout (~233 MB peak, temporal overlays):
  u16*   xn1hi = (u16*)(ws + 0);          // 8MB   ┐
  u16*   xn1lo = (u16*)(ws + 8 * MB);     // 8MB   │ dead after attn/WO →
  float* qb    = (float*)(ws + 16 * MB);  // 16MB  │ h1 (64MB) overlays [0,64)
  float* kb    = (float*)(ws + 32 * MB);  // 16MB  │
  float* vb    = (float*)(ws + 48 * MB);  // 16MB  ┘
  u16*   h1    = (u16*)(ws + 0);
  u16*   ctxhi = (u16*)(ws + 64 * MB);    // 8MB  ┐ dead after WO →
  u16*   ctxlo = (u16*)(ws + 72 * MB);    // 8MB  ┘ gates+meta overlay
  float* gates = (float*)(ws + 64 * MB);
  char*  meta  = ws + 64 * MB + 256 * 1024;
  int4*  sched = (int4*)meta;
  int*   cnt   = (int*)(meta + 2048);
  int*   fill  = cnt + 8;
  int*   offs  = fill + 8;
  float* pacc  = (float*)(offs + 16);
  int*   topk  = (int*)(pacc + 8);
  int*   tlist = topk + 8192;
  u16*   wT    = (u16*)(ws + 80 * MB);    // 8 x 2MB hi/lo ┐ dead after WO →
  u16*   wqhiT = wT;              u16* wqloT = wT + 1 * 1048576;
  u16*   wkhiT = wT + 2 * 1048576; u16* wkloT = wT + 3 * 1048576;
  u16*   wvhiT = wT + 4 * 1048576; u16* wvloT = wT + 5 * 1048576;
  u16*   wohiT = wT + 6 * 1048576; u16* woloT = wT + 7 * 1048576;
  float* xn2f  = (float*)(ws + 80 * MB);  // 16MB, overlays dead wT
  float2* rtab = (float2*)(ws + 96 * MB); // 256KB
  u16*   xn2hi = (u16*)(ws + 97 * MB);    // 8MB
  u16*   w1T   = (u16*)(ws + 105 * MB);   // 64MB
  u16*   w2T   = (u16*)(ws + 169 * MB);   // 64MB -> peak 233MB

  // 0. rope table + weight hi/lo transposes
  ropetab_kernel<<<128, 256, 0, stream>>>(rtab);
  transcast_hilo_kernel<<<dim3(32, 32), dim3(32, 8), 0, stream>>>(wq, wqhiT, wqloT, HDIM, HDIM);
  transcast_hilo_kernel<<<dim3(32, 32), dim3(32, 8), 0, stream>>>(wk, wkhiT, wkloT, HDIM, HDIM);
  transcast_hilo_kernel<<<dim3(32, 32), dim3(32, 8), 0, stream>>>(wv, wvhiT, wvloT, HDIM, HDIM);
  transcast_hilo_kernel<<<dim3(32, 32), dim3(32, 8), 0, stream>>>(wo, wohiT, woloT, HDIM, HDIM);
  // 1. xn1 = rmsnorm(x, g_attn) -> bf16 hi/lo
  rmsnorm_kernel<<<NTOK, 256, 0, stream>>>(x, g_attn, nullptr, xn1hi, xn1lo);
  // 2. fused QKV split-bf16 MFMA GEMM + rope epilogue
  gemm3_qkv_kernel<<<dim3(24, 32), 256, 0, stream>>>(
      xn1hi, xn1lo, wqhiT, wqloT, wkhiT, wkloT, wvhiT, wvloT, qb, kb, vb, rtab);
  // 3. attention (fp32) -> ctx bf16 hi/lo
  attn_kernel<<<dim3(16, 64), 256, 0, stream>>>(qb, kb, vb, ctxhi, ctxlo);
  // 4. x2 = x + ctx @ wo  (split-bf16 MFMA)
  gemm3_wo_kernel<<<dim3(8, 32), 256, 0, stream>>>(ctxhi, ctxlo, wohiT, woloT, x, out);
  // 5. xn2 = rmsnorm(x2, g_ffn): fp32 (router) + bf16 hi (MoE A)
  rmsnorm_kernel<<<NTOK, 256, 0, stream>>>(out, g_ffn, xn2f, xn2hi, nullptr);
  // 6. routing
  init_meta_kernel<<<1, 64, 0, stream>>>(cnt, fill, pacc);
  router_kernel<<<64, 256, 0, stream>>>(xn2f, w_router, gates, topk, cnt, pacc);
  build_schedule_kernel<<<1, 1, 0, stream>>>(cnt, offs, sched);
  scatter_kernel<<<16, 256, 0, stream>>>(topk, offs, fill, tlist);
  // 7. MoE weights -> bf16 [n][k]
  transcast_kernel<<<dim3(128, 32, 8), dim3(32, 8), 0, stream>>>(w1, w1T, HDIM, FF);
  transcast_kernel<<<dim3(32, 128, 8), dim3(32, 8), 0, stream>>>(w2, w2T, FF, HDIM);
  // 8. expert GEMMs
  moe_gemm_kernel<0><<<dim3(FF / 128, MAXTILE), 256, 0, stream>>>(
      xn2hi, w1T, tlist, gates, h1, out, sched);
  moe_gemm_kernel<1><<<dim3(HDIM / 128, MAXTILE), 256, 0, stream>>>(
      h1, w2T, tlist, gates, nullptr, out, sched);
  // 9. aux loss
  aux_kernel<<<1, 1, 0, stream>>>(cnt, pacc, out);
}

// Round 3
// 1386.673 us; speedup vs baseline: 1.5333x; 1.3074x over previous
//
#include <hip/hip_runtime.h>
#include <cstdint>
#include <cstddef>

// ---------------------------------------------------------------------------
// JetFFNMoEBlock. Precision: router-feeding path must stay fp32-accurate
// (logit gaps ~1e-4; flips cost ~0.2 absmax vs 0.1175 threshold). Projection
// GEMMs use split-bf16 MFMA (3-term hi/lo: error ~2^-17, fp32-class).
// R3: attention also split-bf16 MFMA (QK^T + PV, 3-term each) with balanced
// q-tile pairing. Expert GEMMs plain bf16 MFMA (post-selection, safe).
// ---------------------------------------------------------------------------

typedef unsigned short u16;
typedef __attribute__((ext_vector_type(8))) short bf16x8;
typedef __attribute__((ext_vector_type(4))) float f32x4;

#define HDIM 1024
#define NTOK 4096
#define SEQ  1024
#define FF 4096
#define MAXTILE 72

__device__ __forceinline__ u16 f2bf(float f) {
  uint32_t u = __float_as_uint(f);
  u = (u + 0x7FFFu + ((u >> 16) & 1u)) >> 16;   // RNE
  return (u16)u;
}
__device__ __forceinline__ float bf2f(u16 h) {
  return __uint_as_float((uint32_t)h << 16);
}
// trunc-hi + RNE-lo split: |f - hi - lo| <= 2^-17 |f|
__device__ __forceinline__ void split2(float f, u16& hi, u16& lo) {
  uint32_t u = __float_as_uint(f);
  hi = (u16)(u >> 16);
  lo = f2bf(f - __uint_as_float(u & 0xFFFF0000u));
}

__device__ __forceinline__ float gelu_f(float x) {
  float u = 0.7978845608028654f * (x + 0.044715f * x * x * x);
  float ex = __expf(2.0f * u);
  return 0.5f * x * (1.0f + (1.0f - 2.0f / (ex + 1.0f)));
}

// ---------------------------------------------------------------------------
// RoPE cos/sin table [1024 pos][32 d], f64-accurate (matches numpy rounding).
// ---------------------------------------------------------------------------
__global__ void ropetab_kernel(float2* __restrict__ rt) {
  int idx = blockIdx.x * 256 + threadIdx.x;   // 32768
  int s = idx >> 5, d = idx & 31;
  double inv = pow(10000.0, -(double)d / 32.0);
  double ang = (double)s * inv;
  rt[idx] = make_float2((float)cos(ang), (float)sin(ang));
}

// ---------------------------------------------------------------------------
// RMSNorm: one block per row of 1024. Optional fp32 / bf16-hi / bf16-lo outs.
// ---------------------------------------------------------------------------
__global__ __launch_bounds__(256) void rmsnorm_kernel(
    const float* __restrict__ x, const float* __restrict__ g,
    float* __restrict__ outf, u16* __restrict__ outhi, u16* __restrict__ outlo) {
  int row = blockIdx.x;
  int t = threadIdx.x;
  const float4 xv = ((const float4*)(x + (size_t)row * HDIM))[t];
  float ss = xv.x * xv.x + xv.y * xv.y + xv.z * xv.z + xv.w * xv.w;
#pragma unroll
  for (int off = 32; off; off >>= 1) ss += __shfl_xor(ss, off);
  __shared__ float wsum[4];
  if ((t & 63) == 0) wsum[t >> 6] = ss;
  __syncthreads();
  float tot = wsum[0] + wsum[1] + wsum[2] + wsum[3];
  float scale = 1.0f / sqrtf(tot * (1.0f / HDIM) + 1e-5f);
  const float4 gv = ((const float4*)g)[t];
  float o[4] = {xv.x * scale * gv.x, xv.y * scale * gv.y,
                xv.z * scale * gv.z, xv.w * scale * gv.w};
  if (outf) *(float4*)(outf + (size_t)row * HDIM + t * 4) = make_float4(o[0], o[1], o[2], o[3]);
  u16 h[4];
#pragma unroll
  for (int i = 0; i < 4; i++) h[i] = f2bf(o[i]);
  if (outhi) {
    uint2 p;
    p.x = (uint32_t)h[0] | ((uint32_t)h[1] << 16);
    p.y = (uint32_t)h[2] | ((uint32_t)h[3] << 16);
    ((uint2*)(outhi + (size_t)row * HDIM))[t] = p;
  }
  if (outlo) {
    uint2 p;
    u16 lo[4];
#pragma unroll
    for (int i = 0; i < 4; i++) lo[i] = f2bf(o[i] - bf2f(h[i]));
    p.x = (uint32_t)lo[0] | ((uint32_t)lo[1] << 16);
    p.y = (uint32_t)lo[2] | ((uint32_t)lo[3] << 16);
    ((uint2*)(outlo + (size_t)row * HDIM))[t] = p;
  }
}

// ---------------------------------------------------------------------------
// Weight transpose+cast fp32 [R][C] -> bf16 hi/lo [C][R]  (K-contiguous B^T).
// ---------------------------------------------------------------------------
__global__ void transcast_hilo_kernel(const float* __restrict__ in,
                                      u16* __restrict__ ohi, u16* __restrict__ olo,
                                      int R, int C) {
  __shared__ float tile[32][33];
  int c0 = blockIdx.x * 32, r0 = blockIdx.y * 32;
  int tx = threadIdx.x, ty = threadIdx.y;
#pragma unroll
  for (int i = 0; i < 4; i++)
    tile[ty + 8 * i][tx] = in[(size_t)(r0 + ty + 8 * i) * C + c0 + tx];
  __syncthreads();
#pragma unroll
  for (int i = 0; i < 4; i++) {
    float vv = tile[tx][ty + 8 * i];
    u16 h = f2bf(vv);
    size_t oidx = (size_t)(c0 + ty + 8 * i) * R + r0 + tx;
    ohi[oidx] = h;
    olo[oidx] = f2bf(vv - bf2f(h));
  }
}

// single-bf16 version (MoE weights), per-expert via blockIdx.z
__global__ void transcast_kernel(const float* __restrict__ in,
                                 u16* __restrict__ out, int R, int C) {
  __shared__ float tile[32][33];
  size_t eo = (size_t)blockIdx.z * R * C;
  int c0 = blockIdx.x * 32, r0 = blockIdx.y * 32;
  int tx = threadIdx.x, ty = threadIdx.y;
#pragma unroll
  for (int i = 0; i < 4; i++)
    tile[ty + 8 * i][tx] = in[eo + (size_t)(r0 + ty + 8 * i) * C + c0 + tx];
  __syncthreads();
#pragma unroll
  for (int i = 0; i < 4; i++)
    out[eo + (size_t)(c0 + ty + 8 * i) * R + r0 + tx] = f2bf(tile[tx][ty + 8 * i]);
}

// ---------------------------------------------------------------------------
// Split-bf16 MFMA GEMM main loop: acc += AhiBhi + AloBhi + AhiBlo over K=1024.
// 128x128 tile, BK=64, 4 waves, 4x4 of 16x16x32 MFMAs per wave.
// ---------------------------------------------------------------------------
__device__ __forceinline__ void g3_loop(
    const u16* __restrict__ Ahi, const u16* __restrict__ Alo,
    const u16* __restrict__ BH, const u16* __restrict__ BL,
    int m0, int n0, u16 (&As)[128][72], u16 (&Bs)[128][72],
    f32x4 (&acc)[4][4]) {
  const int K = HDIM;
  int t = threadIdx.x, lane = t & 63, wid = t >> 6;
  int wm = wid & 1, wn = wid >> 1;
  int frow = lane & 15, fq = lane >> 4;
  const u16* Aps[3] = {Ahi, Alo, Ahi};
  const u16* Bps[3] = {BH, BH, BL};
#pragma unroll 1
  for (int p = 0; p < 3; p++) {
    const u16* Ap = Aps[p];
    const u16* Bp = Bps[p];
    for (int k0 = 0; k0 < K; k0 += 64) {
      __syncthreads();
#pragma unroll
      for (int pp = 0; pp < 4; pp++) {
        int idx = t + 256 * pp;
        int row = idx >> 3, ch = idx & 7;
        *(uint4*)&As[row][ch * 8] =
            *(const uint4*)(Ap + (size_t)(m0 + row) * K + k0 + ch * 8);
        *(uint4*)&Bs[row][ch * 8] =
            *(const uint4*)(Bp + (size_t)(n0 + row) * K + k0 + ch * 8);
      }
      __syncthreads();
#pragma unroll
      for (int c = 0; c < 2; c++) {
        bf16x8 af[4], bfr[4];
#pragma unroll
        for (int i = 0; i < 4; i++)
          af[i] = *(const bf16x8*)&As[wm * 64 + i * 16 + frow][c * 32 + fq * 8];
#pragma unroll
        for (int j = 0; j < 4; j++)
          bfr[j] = *(const bf16x8*)&Bs[wn * 64 + j * 16 + frow][c * 32 + fq * 8];
#pragma unroll
        for (int i = 0; i < 4; i++)
#pragma unroll
          for (int j = 0; j < 4; j++)
            acc[i][j] = __builtin_amdgcn_mfma_f32_16x16x32_bf16(
                af[i], bfr[j], acc[i][j], 0, 0, 0);
      }
    }
  }
}

// QKV fused: grid.x = 24 n-tiles (0-7 q, 8-15 k, 16-23 v); rope fused for q,k.
__global__ __launch_bounds__(256) void gemm3_qkv_kernel(
    const u16* __restrict__ Ahi, const u16* __restrict__ Alo,
    const u16* __restrict__ WqH, const u16* __restrict__ WqL,
    const u16* __restrict__ WkH, const u16* __restrict__ WkL,
    const u16* __restrict__ WvH, const u16* __restrict__ WvL,
    float* __restrict__ qb, float* __restrict__ kb, float* __restrict__ vb,
    const float2* __restrict__ rtab) {
  __shared__ __align__(16) u16 As[128][72];
  __shared__ __align__(16) u16 Bs[128][72];
  int cls = blockIdx.x >> 3;
  int n0 = (blockIdx.x & 7) * 128, m0 = blockIdx.y * 128;
  const u16* BH = cls == 0 ? WqH : (cls == 1 ? WkH : WvH);
  const u16* BL = cls == 0 ? WqL : (cls == 1 ? WkL : WvL);
  float* outp = cls == 0 ? qb : (cls == 1 ? kb : vb);
  f32x4 acc[4][4];
#pragma unroll
  for (int i = 0; i < 4; i++)
#pragma unroll
    for (int j = 0; j < 4; j++)
#pragma unroll
      for (int r = 0; r < 4; r++) acc[i][j][r] = 0.0f;
  g3_loop(Ahi, Alo, BH, BL, m0, n0, As, Bs, acc);
  int t = threadIdx.x, lane = t & 63, wid = t >> 6;
  int wm = wid & 1, wn = wid >> 1, frow = lane & 15, fq = lane >> 4;
#pragma unroll
  for (int i = 0; i < 4; i++)
#pragma unroll
    for (int r = 0; r < 4; r++) {
      int row = m0 + wm * 64 + i * 16 + fq * 4 + r;
      int s = row & (SEQ - 1);
      if (cls < 2) {
#pragma unroll
        for (int j = 0; j < 2; j++) {          // pair (d, d+32) = (j, j+2)
          int d = j * 16 + frow;               // in-head dim, < 32
          int col = n0 + wn * 64 + j * 16 + frow;
          float2 cs = rtab[s * 32 + d];
          float a = acc[i][j][r], b2 = acc[i][j + 2][r];
          outp[(size_t)row * HDIM + col]      = a * cs.x - b2 * cs.y;
          outp[(size_t)row * HDIM + col + 32] = b2 * cs.x + a * cs.y;
        }
      } else {
#pragma unroll
        for (int j = 0; j < 4; j++)
          outp[(size_t)row * HDIM + n0 + wn * 64 + j * 16 + frow] = acc[i][j][r];
      }
    }
}

// WO: out = ctx @ wo + x  (fp32 out = x2, the residual stream)
__global__ __launch_bounds__(256) void gemm3_wo_kernel(
    const u16* __restrict__ Ahi, const u16* __restrict__ Alo,
    const u16* __restrict__ WH, const u16* __restrict__ WL,
    const float* __restrict__ resid, float* __restrict__ outp) {
  __shared__ __align__(16) u16 As[128][72];
  __shared__ __align__(16) u16 Bs[128][72];
  int n0 = blockIdx.x * 128, m0 = blockIdx.y * 128;
  f32x4 acc[4][4];
#pragma unroll
  for (int i = 0; i < 4; i++)
#pragma unroll
    for (int j = 0; j < 4; j++)
#pragma unroll
      for (int r = 0; r < 4; r++) acc[i][j][r] = 0.0f;
  g3_loop(Ahi, Alo, WH, WL, m0, n0, As, Bs, acc);
  int t = threadIdx.x, lane = t & 63, wid = t >> 6;
  int wm = wid & 1, wn = wid >> 1, frow = lane & 15, fq = lane >> 4;
#pragma unroll
  for (int i = 0; i < 4; i++)
#pragma unroll
    for (int r = 0; r < 4; r++) {
      int row = m0 + wm * 64 + i * 16 + fq * 4 + r;
#pragma unroll
      for (int j = 0; j < 4; j++) {
        size_t off = (size_t)row * HDIM + n0 + wn * 64 + j * 16 + frow;
        outp[off] = acc[i][j][r] + resid[off];
      }
    }
}

// ---------------------------------------------------------------------------
// MFMA flash attention, causal, D=64, q-tile 64. Split-bf16 3-term QK^T and
// PV (pair error ~2^-17 -> router-safe). Balanced pairing: block (p,bh) does
// q-tiles {p, 15-p} = constant 17 kt-iters. P overlays the K LDS buffers
// (intra-wave write->read; LDS ops are wave-ordered). 55.3 KB LDS ->
// 2 blocks/CU, grid 512 = all resident, no tail.
// ---------------------------------------------------------------------------
__global__ __launch_bounds__(256) void attn_kernel(
    const float* __restrict__ q, const float* __restrict__ k,
    const float* __restrict__ v, u16* __restrict__ ctxhi,
    u16* __restrict__ ctxlo) {
  __shared__ __align__(16) u16 Qhi[64][72], Qlo[64][72];
  __shared__ __align__(16) u16 Khi[64][72], Klo[64][72];   // K tile; P after QK
  __shared__ __align__(16) u16 Vthi[64][72], Vtlo[64][72]; // [d][key]
  int t = threadIdx.x, lane = t & 63, w = t >> 6;
  int frow = lane & 15, fq = lane >> 4;
  int p = blockIdx.x, bh = blockIdx.y;
  int b = bh >> 4, hh = bh & 15;
  const size_t base = (size_t)b * SEQ * HDIM + hh * 64;

  for (int half = 0; half < 2; half++) {
    int qt = (half == 0) ? p : 15 - p;
    __syncthreads();   // prior subtile LDS use complete
    // ---- load Q tile -> Qhi/Qlo
#pragma unroll
    for (int pp = 0; pp < 4; pp++) {
      int idx = t + 256 * pp;
      int row = idx >> 4, d4 = idx & 15;
      float4 qv = *(const float4*)(q + base + (size_t)(qt * 64 + row) * HDIM + d4 * 4);
      float qf[4] = {qv.x, qv.y, qv.z, qv.w};
      u16 qh[4], ql[4];
#pragma unroll
      for (int c = 0; c < 4; c++) split2(qf[c], qh[c], ql[c]);
      uint2 ph, pl;
      ph.x = (uint32_t)qh[0] | ((uint32_t)qh[1] << 16);
      ph.y = (uint32_t)qh[2] | ((uint32_t)qh[3] << 16);
      pl.x = (uint32_t)ql[0] | ((uint32_t)ql[1] << 16);
      pl.y = (uint32_t)ql[2] | ((uint32_t)ql[3] << 16);
      *(uint2*)&Qhi[row][d4 * 4] = ph;
      *(uint2*)&Qlo[row][d4 * 4] = pl;
    }
    float m[4], l[4];
    f32x4 o[4];
#pragma unroll
    for (int r = 0; r < 4; r++) { m[r] = -1e30f; l[r] = 0.0f; }
#pragma unroll
    for (int d = 0; d < 4; d++)
#pragma unroll
      for (int r = 0; r < 4; r++) o[d][r] = 0.0f;
    // preload K/V tile 0 into regs
    float4 kreg[4], vreg[4];
#pragma unroll
    for (int pp = 0; pp < 4; pp++) {
      int idx = t + 256 * pp;
      int row = idx >> 4, d4 = idx & 15;
      kreg[pp] = *(const float4*)(k + base + (size_t)row * HDIM + d4 * 4);
      vreg[pp] = *(const float4*)(v + base + (size_t)row * HDIM + d4 * 4);
    }

    for (int kt = 0; kt <= qt; kt++) {
      __syncthreads();   // prev iter PV reads done (and Q write visible below)
      // ---- store K/V tile: K row-major hi/lo, V transposed [d][key] hi/lo
#pragma unroll
      for (int pp = 0; pp < 4; pp++) {
        int idx = t + 256 * pp;
        int row = idx >> 4, d4 = idx & 15;
        float kf[4] = {kreg[pp].x, kreg[pp].y, kreg[pp].z, kreg[pp].w};
        u16 kh[4], kl[4];
#pragma unroll
        for (int c = 0; c < 4; c++) split2(kf[c], kh[c], kl[c]);
        uint2 ph, pl;
        ph.x = (uint32_t)kh[0] | ((uint32_t)kh[1] << 16);
        ph.y = (uint32_t)kh[2] | ((uint32_t)kh[3] << 16);
        pl.x = (uint32_t)kl[0] | ((uint32_t)kl[1] << 16);
        pl.y = (uint32_t)kl[2] | ((uint32_t)kl[3] << 16);
        *(uint2*)&Khi[row][d4 * 4] = ph;
        *(uint2*)&Klo[row][d4 * 4] = pl;
        float vf[4] = {vreg[pp].x, vreg[pp].y, vreg[pp].z, vreg[pp].w};
#pragma unroll
        for (int c = 0; c < 4; c++) {
          u16 vh, vl;
          split2(vf[c], vh, vl);
          Vthi[d4 * 4 + c][row] = vh;
          Vtlo[d4 * 4 + c][row] = vl;
        }
      }
      __syncthreads();
      if (kt < qt) {   // prefetch next K/V tile
#pragma unroll
        for (int pp = 0; pp < 4; pp++) {
          int idx = t + 256 * pp;
          int row = idx >> 4, d4 = idx & 15;
          kreg[pp] = *(const float4*)(k + base + (size_t)((kt + 1) * 64 + row) * HDIM + d4 * 4);
          vreg[pp] = *(const float4*)(v + base + (size_t)((kt + 1) * 64 + row) * HDIM + d4 * 4);
        }
      }
      // ---- QK^T: wave w -> q rows [16w,16w+16), all 64 cols. 3-term MFMA.
      f32x4 s[4];
#pragma unroll
      for (int j = 0; j < 4; j++)
#pragma unroll
        for (int r = 0; r < 4; r++) s[j][r] = 0.0f;
#pragma unroll
      for (int c = 0; c < 2; c++) {
        bf16x8 aH = *(const bf16x8*)&Qhi[w * 16 + frow][c * 32 + fq * 8];
        bf16x8 aL = *(const bf16x8*)&Qlo[w * 16 + frow][c * 32 + fq * 8];
#pragma unroll
        for (int j = 0; j < 4; j++) {
          bf16x8 bH = *(const bf16x8*)&Khi[j * 16 + frow][c * 32 + fq * 8];
          bf16x8 bL = *(const bf16x8*)&Klo[j * 16 + frow][c * 32 + fq * 8];
          s[j] = __builtin_amdgcn_mfma_f32_16x16x32_bf16(aH, bH, s[j], 0, 0, 0);
          s[j] = __builtin_amdgcn_mfma_f32_16x16x32_bf16(aL, bH, s[j], 0, 0, 0);
          s[j] = __builtin_amdgcn_mfma_f32_16x16x32_bf16(aH, bL, s[j], 0, 0, 0);
        }
      }
      // ---- mask + online softmax. Row = w*16 + 4*fq + r, col = j*16 + frow.
      float alpha[4];
#pragma unroll
      for (int r = 0; r < 4; r++) {
        int qg = qt * 64 + w * 16 + 4 * fq + r;
        float sv[4];
#pragma unroll
        for (int j = 0; j < 4; j++) {
          int kg = kt * 64 + j * 16 + frow;
          float sc = s[j][r] * 0.125f;
          sv[j] = (kg > qg) ? -1e9f : sc;
        }
        float mx = fmaxf(fmaxf(sv[0], sv[1]), fmaxf(sv[2], sv[3]));
        mx = fmaxf(mx, __shfl_xor(mx, 1));
        mx = fmaxf(mx, __shfl_xor(mx, 2));
        mx = fmaxf(mx, __shfl_xor(mx, 4));
        mx = fmaxf(mx, __shfl_xor(mx, 8));
        float mn = fmaxf(m[r], mx);
        float sum = 0.0f;
#pragma unroll
        for (int j = 0; j < 4; j++) {
          sv[j] = __expf(sv[j] - mn);
          sum += sv[j];
        }
        sum += __shfl_xor(sum, 1);
        sum += __shfl_xor(sum, 2);
        sum += __shfl_xor(sum, 4);
        sum += __shfl_xor(sum, 8);
        alpha[r] = __expf(m[r] - mn);
        l[r] = l[r] * alpha[r] + sum;
        m[r] = mn;
#pragma unroll
        for (int j = 0; j < 4; j++) s[j][r] = sv[j];
      }
#pragma unroll
      for (int d = 0; d < 4; d++)
#pragma unroll
        for (int r = 0; r < 4; r++) o[d][r] *= alpha[r];
      __syncthreads();   // all waves' QK reads of Khi/Klo complete
      // ---- write P (hi/lo) into K buffers, own 16-row strip only
#pragma unroll
      for (int j = 0; j < 4; j++)
#pragma unroll
        for (int r = 0; r < 4; r++) {
          u16 ph, pl;
          split2(s[j][r], ph, pl);
          Khi[w * 16 + 4 * fq + r][j * 16 + frow] = ph;
          Klo[w * 16 + 4 * fq + r][j * 16 + frow] = pl;
        }
      // ---- PV: o[d] += P @ Vt, 3-term. Intra-wave LDS ordering: no barrier.
#pragma unroll
      for (int c = 0; c < 2; c++) {
        bf16x8 aH = *(const bf16x8*)&Khi[w * 16 + frow][c * 32 + fq * 8];
        bf16x8 aL = *(const bf16x8*)&Klo[w * 16 + frow][c * 32 + fq * 8];
#pragma unroll
        for (int d = 0; d < 4; d++) {
          bf16x8 bH = *(const bf16x8*)&Vthi[d * 16 + frow][c * 32 + fq * 8];
          bf16x8 bL = *(const bf16x8*)&Vtlo[d * 16 + frow][c * 32 + fq * 8];
          o[d] = __builtin_amdgcn_mfma_f32_16x16x32_bf16(aH, bH, o[d], 0, 0, 0);
          o[d] = __builtin_amdgcn_mfma_f32_16x16x32_bf16(aL, bH, o[d], 0, 0, 0);
          o[d] = __builtin_amdgcn_mfma_f32_16x16x32_bf16(aH, bL, o[d], 0, 0, 0);
        }
      }
    }
    // ---- epilogue: ctx = o/l -> bf16 hi/lo
#pragma unroll
    for (int r = 0; r < 4; r++) {
      float linv = 1.0f / l[r];
      int row = qt * 64 + w * 16 + 4 * fq + r;
#pragma unroll
      for (int d = 0; d < 4; d++) {
        float vv = o[d][r] * linv;
        u16 h, lo2;
        split2(vv, h, lo2);
        size_t addr = base + (size_t)row * HDIM + d * 16 + frow;
        ctxhi[addr] = h;
        ctxlo[addr] = lo2;
      }
    }
  }
}

// ---------------------------------------------------------------------------
// Router (fp32, exact top-2 semantics) + schedule + scatter + aux. Unchanged.
// ---------------------------------------------------------------------------
__global__ __launch_bounds__(256) void router_kernel(
    const float* __restrict__ xn, const float* __restrict__ wr,
    float* __restrict__ gates, int* __restrict__ topk,
    int* __restrict__ cnt, float* __restrict__ pacc) {
  int wid = threadIdx.x >> 6, lane = threadIdx.x & 63;
  float localP[8] = {};
  int localC[8] = {};
  for (int i = 0; i < 16; i++) {
    int t = blockIdx.x * 64 + wid * 16 + i;
    const float* xr = xn + (size_t)t * HDIM;
    float p[8] = {};
    for (int h = lane; h < HDIM; h += 64) {
      float xv = xr[h];
      const float* wrow = wr + h * 8;
#pragma unroll
      for (int e = 0; e < 8; e++) p[e] += xv * wrow[e];
    }
#pragma unroll
    for (int e = 0; e < 8; e++)
#pragma unroll
      for (int off = 32; off; off >>= 1) p[e] += __shfl_xor(p[e], off);
    if (lane == 0) {
      float m = p[0];
#pragma unroll
      for (int e = 1; e < 8; e++) m = fmaxf(m, p[e]);
      float s = 0.0f;
#pragma unroll
      for (int e = 0; e < 8; e++) { p[e] = expf(p[e] - m); s += p[e]; }
      float invs = 1.0f / s;
#pragma unroll
      for (int e = 0; e < 8; e++) p[e] *= invs;
      int i1 = 0; float b1 = p[0];
#pragma unroll
      for (int e = 1; e < 8; e++) if (p[e] > b1) { b1 = p[e]; i1 = e; }
      int i2 = -1; float b2 = -1.0f;
#pragma unroll
      for (int e = 0; e < 8; e++) if (e != i1 && p[e] > b2) { b2 = p[e]; i2 = e; }
      float gden = 1.0f / (b1 + b2);
#pragma unroll
      for (int e = 0; e < 8; e++)
        gates[(size_t)t * 8 + e] = (e == i1) ? b1 * gden : ((e == i2) ? b2 * gden : 0.0f);
      topk[t * 2] = i1; topk[t * 2 + 1] = i2;
      localC[i1]++; localC[i2]++;
#pragma unroll
      for (int e = 0; e < 8; e++) localP[e] += p[e];
    }
  }
  if (lane == 0) {
#pragma unroll
    for (int e = 0; e < 8; e++) {
      atomicAdd(&cnt[e], localC[e]);
      atomicAdd(&pacc[e], localP[e]);
    }
  }
}

__global__ void init_meta_kernel(int* cnt, int* fill, float* pacc) {
  int t = threadIdx.x;
  if (t < 8) { cnt[t] = 0; fill[t] = 0; pacc[t] = 0.0f; }
}

__global__ void build_schedule_kernel(const int* __restrict__ cnt,
                                      int* __restrict__ offs,
                                      int4* __restrict__ sched) {
  int off = 0, idx = 0;
  for (int e = 0; e < 8; e++) {
    offs[e] = off;
    int c = cnt[e];
    for (int r = 0; r < c; r += 128) {
      sched[idx] = make_int4(e, off + r, (c - r) < 128 ? (c - r) : 128, 0);
      idx++;
    }
    off += c;
  }
  offs[8] = off;
  for (; idx < MAXTILE; idx++) sched[idx] = make_int4(-1, 0, 0, 0);
}

__global__ __launch_bounds__(256) void scatter_kernel(
    const int* __restrict__ topk, const int* __restrict__ offs,
    int* __restrict__ fill, int* __restrict__ tlist) {
  int t = blockIdx.x * 256 + threadIdx.x;
  int i1 = topk[t * 2], i2 = topk[t * 2 + 1];
  int s1 = atomicAdd(&fill[i1], 1);
  tlist[offs[i1] + s1] = t;
  int s2 = atomicAdd(&fill[i2], 1);
  tlist[offs[i2] + s2] = t;
}

__global__ void aux_kernel(const int* __restrict__ cnt,
                           const float* __restrict__ pacc,
                           float* __restrict__ dout) {
  float a = 0.0f;
  for (int e = 0; e < 8; e++)
    a += ((float)cnt[e] / (NTOK * 2.0f)) * (pacc[e] / (float)NTOK);
  dout[(size_t)NTOK * HDIM] = 8.0f * a;
}

// ---------------------------------------------------------------------------
// bf16 MFMA GEMM over routed token tiles (unchanged, passing).
// ---------------------------------------------------------------------------
template <int MODE>
__global__ __launch_bounds__(256) void moe_gemm_kernel(
    const u16* __restrict__ Abase, const u16* __restrict__ Bbase,
    const int* __restrict__ tlist, const float* __restrict__ gates,
    u16* __restrict__ h1out, float* __restrict__ dout,
    const int4* __restrict__ sched) {
  int4 sc = sched[blockIdx.y];
  int e = sc.x;
  if (e < 0) return;
  int gslot0 = sc.y, nrows = sc.z;
  const int K = (MODE == 0) ? HDIM : FF;
  int n0 = blockIdx.x * 128;
  const u16* Bp = Bbase + (size_t)e * FF * HDIM;
  __shared__ __align__(16) u16 As[128][72];
  __shared__ __align__(16) u16 Bs[128][72];
  int t = threadIdx.x, lane = t & 63, wid = t >> 6;
  int wm = wid & 1, wn = wid >> 1;
  int frow = lane & 15, fq = lane >> 4;
  f32x4 acc[4][4];
#pragma unroll
  for (int i = 0; i < 4; i++)
#pragma unroll
    for (int j = 0; j < 4; j++)
#pragma unroll
      for (int r = 0; r < 4; r++) acc[i][j][r] = 0.0f;

  int arow_idx[4];
#pragma unroll
  for (int p = 0; p < 4; p++) {
    int row = (t + 256 * p) >> 3;
    if (MODE == 0)
      arow_idx[p] = (row < nrows) ? tlist[gslot0 + row] : -1;
    else
      arow_idx[p] = (row < nrows) ? (gslot0 + row) : -1;
  }

  for (int k0 = 0; k0 < K; k0 += 64) {
    __syncthreads();
#pragma unroll
    for (int p = 0; p < 4; p++) {
      int idx = t + 256 * p;
      int row = idx >> 3, ch = idx & 7;
      uint4 av = make_uint4(0u, 0u, 0u, 0u);
      if (arow_idx[p] >= 0)
        av = *(const uint4*)(Abase + (size_t)arow_idx[p] * K + k0 + ch * 8);
      *(uint4*)&As[row][ch * 8] = av;
      uint4 bv = *(const uint4*)(Bp + (size_t)(n0 + row) * K + k0 + ch * 8);
      *(uint4*)&Bs[row][ch * 8] = bv;
    }
    __syncthreads();
#pragma unroll
    for (int c = 0; c < 2; c++) {
      bf16x8 af[4], bfr[4];
#pragma unroll
      for (int i = 0; i < 4; i++)
        af[i] = *(const bf16x8*)&As[wm * 64 + i * 16 + frow][c * 32 + fq * 8];
#pragma unroll
      for (int j = 0; j < 4; j++)
        bfr[j] = *(const bf16x8*)&Bs[wn * 64 + j * 16 + frow][c * 32 + fq * 8];
#pragma unroll
      for (int i = 0; i < 4; i++)
#pragma unroll
        for (int j = 0; j < 4; j++)
          acc[i][j] = __builtin_amdgcn_mfma_f32_16x16x32_bf16(af[i], bfr[j],
                                                              acc[i][j], 0, 0, 0);
    }
  }
#pragma unroll
  for (int i = 0; i < 4; i++)
#pragma unroll
    for (int j = 0; j < 4; j++) {
      int col = n0 + wn * 64 + j * 16 + frow;
#pragma unroll
      for (int r = 0; r < 4; r++) {
        int lr = wm * 64 + i * 16 + fq * 4 + r;
        if (lr < nrows) {
          float val = acc[i][j][r];
          if (MODE == 0) {
            h1out[(size_t)(gslot0 + lr) * FF + col] = f2bf(gelu_f(val));
          } else {
            int tok = tlist[gslot0 + lr];
            float g = gates[(size_t)tok * 8 + e];
            atomicAdd(&dout[(size_t)tok * HDIM + col], g * val);
          }
        }
      }
    }
}

// ---------------------------------------------------------------------------
extern "C" void kernel_launch(void* const* d_in, const int* in_sizes, int n_in,
                              void* d_out, int out_size, void* d_ws,
                              size_t ws_size, hipStream_t stream) {
  const float* x        = (const float*)d_in[0];
  const float* g_attn   = (const float*)d_in[1];
  const float* wq       = (const float*)d_in[2];
  const float* wk       = (const float*)d_in[3];
  const float* wv       = (const float*)d_in[4];
  const float* wo       = (const float*)d_in[5];
  const float* g_ffn    = (const float*)d_in[6];
  const float* w_router = (const float*)d_in[7];
  const float* w1       = (const float*)d_in[8];
  const float* w2       = (const float*)d_in[9];
  float* out = (float*)d_out;
  char* ws = (char*)d_ws;
  const size_t MB = 1048576;

  // ws layout (~233 MB peak, temporal overlays):
  u16*   xn1hi = (u16*)(ws + 0);          // 8MB   ┐
  u16*   xn1lo = (u16*)(ws + 8 * MB);     // 8MB   │ dead after attn/WO →
  float* qb    = (float*)(ws + 16 * MB);  // 16MB  │ h1 (64MB) overlays [0,64)
  float* kb    = (float*)(ws + 32 * MB);  // 16MB  │
  float* vb    = (float*)(ws + 48 * MB);  // 16MB  ┘
  u16*   h1    = (u16*)(ws + 0);
  u16*   ctxhi = (u16*)(ws + 64 * MB);    // 8MB  ┐ dead after WO →
  u16*   ctxlo = (u16*)(ws + 72 * MB);    // 8MB  ┘ gates+meta overlay
  float* gates = (float*)(ws + 64 * MB);
  char*  meta  = ws + 64 * MB + 256 * 1024;
  int4*  sched = (int4*)meta;
  int*   cnt   = (int*)(meta + 2048);
  int*   fill  = cnt + 8;
  int*   offs  = fill + 8;
  float* pacc  = (float*)(offs + 16);
  int*   topk  = (int*)(pacc + 8);
  int*   tlist = topk + 8192;
  u16*   wT    = (u16*)(ws + 80 * MB);    // 8 x 2MB hi/lo ┐ dead after WO →
  u16*   wqhiT = wT;              u16* wqloT = wT + 1 * 1048576;
  u16*   wkhiT = wT + 2 * 1048576; u16* wkloT = wT + 3 * 1048576;
  u16*   wvhiT = wT + 4 * 1048576; u16* wvloT = wT + 5 * 1048576;
  u16*   wohiT = wT + 6 * 1048576; u16* woloT = wT + 7 * 1048576;
  float* xn2f  = (float*)(ws + 80 * MB);  // 16MB, overlays dead wT
  float2* rtab = (float2*)(ws + 96 * MB); // 256KB
  u16*   xn2hi = (u16*)(ws + 97 * MB);    // 8MB
  u16*   w1T   = (u16*)(ws + 105 * MB);   // 64MB
  u16*   w2T   = (u16*)(ws + 169 * MB);   // 64MB -> peak 233MB

  // 0. rope table + weight hi/lo transposes
  ropetab_kernel<<<128, 256, 0, stream>>>(rtab);
  transcast_hilo_kernel<<<dim3(32, 32), dim3(32, 8), 0, stream>>>(wq, wqhiT, wqloT, HDIM, HDIM);
  transcast_hilo_kernel<<<dim3(32, 32), dim3(32, 8), 0, stream>>>(wk, wkhiT, wkloT, HDIM, HDIM);
  transcast_hilo_kernel<<<dim3(32, 32), dim3(32, 8), 0, stream>>>(wv, wvhiT, wvloT, HDIM, HDIM);
  transcast_hilo_kernel<<<dim3(32, 32), dim3(32, 8), 0, stream>>>(wo, wohiT, woloT, HDIM, HDIM);
  // 1. xn1 = rmsnorm(x, g_attn) -> bf16 hi/lo
  rmsnorm_kernel<<<NTOK, 256, 0, stream>>>(x, g_attn, nullptr, xn1hi, xn1lo);
  // 2. fused QKV split-bf16 MFMA GEMM + rope epilogue
  gemm3_qkv_kernel<<<dim3(24, 32), 256, 0, stream>>>(
      xn1hi, xn1lo, wqhiT, wqloT, wkhiT, wkloT, wvhiT, wvloT, qb, kb, vb, rtab);
  // 3. attention (split-bf16 MFMA, balanced pairing) -> ctx bf16 hi/lo
  attn_kernel<<<dim3(8, 64), 256, 0, stream>>>(qb, kb, vb, ctxhi, ctxlo);
  // 4. x2 = x + ctx @ wo  (split-bf16 MFMA)
  gemm3_wo_kernel<<<dim3(8, 32), 256, 0, stream>>>(ctxhi, ctxlo, wohiT, woloT, x, out);
  // 5. xn2 = rmsnorm(x2, g_ffn): fp32 (router) + bf16 hi (MoE A)
  rmsnorm_kernel<<<NTOK, 256, 0, stream>>>(out, g_ffn, xn2f, xn2hi, nullptr);
  // 6. routing
  init_meta_kernel<<<1, 64, 0, stream>>>(cnt, fill, pacc);
  router_kernel<<<64, 256, 0, stream>>>(xn2f, w_router, gates, topk, cnt, pacc);
  build_schedule_kernel<<<1, 1, 0, stream>>>(cnt, offs, sched);
  scatter_kernel<<<16, 256, 0, stream>>>(topk, offs, fill, tlist);
  // 7. MoE weights -> bf16 [n][k]
  transcast_kernel<<<dim3(128, 32, 8), dim3(32, 8), 0, stream>>>(w1, w1T, HDIM, FF);
  transcast_kernel<<<dim3(32, 128, 8), dim3(32, 8), 0, stream>>>(w2, w2T, FF, HDIM);
  // 8. expert GEMMs
  moe_gemm_kernel<0><<<dim3(FF / 128, MAXTILE), 256, 0, stream>>>(
      xn2hi, w1T, tlist, gates, h1, out, sched);
  moe_gemm_kernel<1><<<dim3(HDIM / 128, MAXTILE), 256, 0, stream>>>(
      h1, w2T, tlist, gates, nullptr, out, sched);
  // 9. aux loss
  aux_kernel<<<1, 1, 0, stream>>>(cnt, pacc, out);
}